// Round 1
// baseline (244.837 us; speedup 1.0000x reference)
//
#include <hip/hip_runtime.h>
#include <math.h>

// Problem constants (from reference setup_inputs)
#define NB     64      // batch
#define N1V    8192    // obj points per batch
#define NPTS   (NB * N1V)
#define NV     778     // recon / gt verts
#define NVP    780     // padded to multiple of 4
#define NQ     195     // target quads
#define SEG1Q  51      // first 51 quads = 204 permuted targets = PRIOR set
#define NFACE  1538
#define NZ     64
#define NPAR   61
#define NPRIOR 204
#define PPT    8       // obj points per thread (rec/gt roles)
#define BIAS   0.0625f // 2|a||t| <= 0.06 < BIAS -> biased rec partials stay >= 0

// Single fused kernel: block roles by blockIdx.x
#define PREP_BLOCKS 64
#define GT_BLOCKS   256
#define REC_BLOCKS  256
#define CH_BLOCKS   128
#define SCAN_BLOCKS (GT_BLOCKS + REC_BLOCKS + CH_BLOCKS)   // 640
#define NBLOCKS     (PREP_BLOCKS + SCAN_BLOCKS)            // 704
#define GT_BASE  PREP_BLOCKS                // 64
#define REC_BASE (GT_BASE + GT_BLOCKS)     // 320
#define CH_BASE  (REC_BASE + REC_BLOCKS)   // 576
// Deadlock-safety: 704 blocks must be co-resident. __launch_bounds__(256,4)
// guarantees >=4 blocks/CU (VGPR<=128); LDS 24KB -> 6/CU. capacity >= 1024 > 704.

// ws float4 layout per batch (BATCH_F4 float4s):
//   [0,780)     gt4    (x,y,z,|t|^2)  original order, pads w=1e30
//   [780,1560)  rec4p  (x,y,z,|t|^2+BIAS) PERMUTED (prior first), pads w=1e30
//   [1560,2340) nrm4p  (nx,ny,nz,0)   PERMUTED to match rec4p
#define BATCH_F4 2352                  // padded stride
// float offsets in ws
#define ACCB_OFF  (NB * BATCH_F4 * 4)        // accB[64][8] per-batch accumulators
#define FLAGS_OFF (ACCB_OFF + NB * 8)        // uint flags: [0,64) prep, [64,320) gt, [320] ticket
#define NFLAGS    (NB + GT_BLOCKS + 1)       // 321
#define GC_OFF    (FLAGS_OFF + NFLAGS + 3)   // uchar[NPTS/8] gt-cmap bits
// accB slots: 0 chamfer, 1 S_cmap, 2 N_cmap, 3 N_gt, 4 N_cons, 5 S_pen

__device__ __constant__ int c_prior[NPRIOR] = {
  697,698,699,700,712,713,714,715,737,738,739,740,741,743,744,745,746,748,749,750,
  753,754,755,756,757,758,759,760,761,762,763,764,765,766,767,768,
  46,47,48,49,164,165,166,167,194,195,223,237,238,280,281,298,301,317,320,323,
  324,325,326,327,328,329,330,331,332,333,340,341,342,343,344,345,346,347,348,349,
  350,351,352,353,354,355,
  356,357,358,359,375,376,386,387,396,397,402,403,413,429,433,434,435,436,437,438,
  439,440,441,442,443,444,452,453,454,455,456,459,460,461,462,463,464,465,466,467,
  468,469,470,471,484,485,486,496,497,506,507,513,514,524,545,546,547,548,549,550,
  551,552,553,555,563,564,565,566,567,570,572,573,574,575,576,577,578,
  580,581,582,583,600,601,602,614,615,624,625,630,631,641,663,664,665,666,667,668,
  670,672,680,681,682,683,684,686,687,688,689,690,691,692,693,694,695,
  73,96,98,99,772,774,775,777
};

struct PrepSh {
    float4 r[NV];
    float vnx[NV], vny[NV], vnz[NV];
    unsigned int bm[25];
    unsigned short pre[26];
    unsigned short perm[NV];
};
struct ScanSh {
    float4 t[NVP];
    float red[8];
};
union ShU { PrepSh prep; ScanSh scan; };

#define LOAD_PTS(ob)                                                          \
    const float4* ob4 = (const float4*)((ob) + (size_t)tid * 24);             \
    float4 q0 = ob4[0], q1 = ob4[1], q2 = ob4[2],                             \
           q3 = ob4[3], q4 = ob4[4], q5 = ob4[5];                             \
    float px[PPT], py[PPT], pz[PPT];                                          \
    px[0]=q0.x; py[0]=q0.y; pz[0]=q0.z;  px[1]=q0.w; py[1]=q1.x; pz[1]=q1.y;  \
    px[2]=q1.z; py[2]=q1.w; pz[2]=q2.x;  px[3]=q2.y; py[3]=q2.z; pz[3]=q2.w;  \
    px[4]=q3.x; py[4]=q3.y; pz[4]=q3.z;  px[5]=q3.w; py[5]=q4.x; pz[5]=q4.y;  \
    px[6]=q4.z; py[6]=q4.w; pz[6]=q5.x;  px[7]=q5.y; py[7]=q5.z; pz[7]=q5.w;

// min3-friendly shapes: LLVM folds fmin(fmin(a,b),c) -> v_min3_f32
__device__ __forceinline__ float min3f(float a, float b, float c) {
    return fminf(fminf(a, b), c);
}

__device__ __forceinline__ void spin_wait(unsigned int* f, int tid) {
    if (tid == 0) {
        while (__hip_atomic_load(f, __ATOMIC_ACQUIRE, __HIP_MEMORY_SCOPE_AGENT) == 0u)
            __builtin_amdgcn_s_sleep(2);
    }
    __syncthreads();   // tid0's acquire invalidated L1; loads below see fresh data
}

__global__ __launch_bounds__(256, 4) void k_all(
        const float* __restrict__ obj,   const float* __restrict__ recon,
        const float* __restrict__ gt,    const int*   __restrict__ faces,
        const float* __restrict__ mean,  const float* __restrict__ log_var,
        const float* __restrict__ rp,    const float* __restrict__ xp,
        float4* __restrict__ ws4,        float* __restrict__ accB,
        unsigned int* __restrict__ flags, unsigned char* __restrict__ gcA,
        float* __restrict__ out) {
    __shared__ ShU sh;
    __shared__ unsigned int s_tk;
    int tid = threadIdx.x, blk = blockIdx.x;

    if (blk < PREP_BLOCKS) {
        // ================= PREP ROLE (per batch) =================
        int b = blk;
        if (tid < 8) accB[b * 8 + tid] = 0.0f;
        if (tid < 25) sh.prep.bm[tid] = 0u;
        __syncthreads();
        if (tid < NPRIOR) {
            int v = c_prior[tid];
            atomicOr(&sh.prep.bm[v >> 5], 1u << (v & 31));
        }
        const float* rb = recon + (size_t)b * NV * 3;
        const float* gb = gt    + (size_t)b * NV * 3;
        float4* gt4   = ws4 + (size_t)b * BATCH_F4;
        float4* rec4p = gt4 + NVP;
        float4* nrm4p = rec4p + NVP;
        for (int j = tid; j < NV; j += 256) {
            float x = rb[3*j], y = rb[3*j+1], z = rb[3*j+2];
            sh.prep.r[j] = make_float4(x, y, z, x*x + y*y + z*z + BIAS);
            x = gb[3*j]; y = gb[3*j+1]; z = gb[3*j+2];
            gt4[j] = make_float4(x, y, z, x*x + y*y + z*z);
            sh.prep.vnx[j] = 0.0f; sh.prep.vny[j] = 0.0f; sh.prep.vnz[j] = 0.0f;
        }
        if (tid < 2) gt4[NV + tid] = make_float4(0.f, 0.f, 0.f, 1e30f);
        __syncthreads();
        if (tid == 0) {
            unsigned int run = 0;
            for (int w = 0; w < 25; ++w) { sh.prep.pre[w] = (unsigned short)run; run += __popc(sh.prep.bm[w]); }
            sh.prep.pre[25] = (unsigned short)run;
        }
        __syncthreads();
        for (int j = tid; j < NV; j += 256) {
            int w = j >> 5;
            unsigned int below = sh.prep.bm[w] & ((1u << (j & 31)) - 1u);
            int rank = sh.prep.pre[w] + __popc(below);
            bool member = (sh.prep.bm[w] >> (j & 31)) & 1u;
            int pos = member ? rank : (NPRIOR + (j - rank));
            sh.prep.perm[pos] = (unsigned short)j;
        }
        for (int f = tid; f < NFACE; f += 256) {
            int i0 = faces[3*f], i1 = faces[3*f+1], i2 = faces[3*f+2];
            float4 p0 = sh.prep.r[i0], p1 = sh.prep.r[i1], p2 = sh.prep.r[i2];
            float e1x = p1.x - p0.x, e1y = p1.y - p0.y, e1z = p1.z - p0.z;
            float e2x = p2.x - p0.x, e2y = p2.y - p0.y, e2z = p2.z - p0.z;
            float fx = e1y * e2z - e1z * e2y;
            float fy = e1z * e2x - e1x * e2z;
            float fz = e1x * e2y - e1y * e2x;
            atomicAdd(&sh.prep.vnx[i0], fx); atomicAdd(&sh.prep.vny[i0], fy); atomicAdd(&sh.prep.vnz[i0], fz);
            atomicAdd(&sh.prep.vnx[i1], fx); atomicAdd(&sh.prep.vny[i1], fy); atomicAdd(&sh.prep.vnz[i1], fz);
            atomicAdd(&sh.prep.vnx[i2], fx); atomicAdd(&sh.prep.vny[i2], fy); atomicAdd(&sh.prep.vnz[i2], fz);
        }
        __syncthreads();
        for (int j = tid; j < NVP; j += 256) {
            if (j < NV) {
                int src = sh.prep.perm[j];
                rec4p[j] = sh.prep.r[src];
                float x = sh.prep.vnx[src], y = sh.prep.vny[src], z = sh.prep.vnz[src];
                float inv = 1.0f / (sqrtf(x*x + y*y + z*z) + 1e-12f);
                nrm4p[j] = make_float4(x * inv, y * inv, z * inv, 0.0f);
            } else {
                rec4p[j] = make_float4(0.f, 0.f, 0.f, 1e30f);
                nrm4p[j] = make_float4(0.f, 0.f, 1.f, 0.0f);
            }
        }
        __syncthreads();
        if (tid == 0) {
            __threadfence();
            __hip_atomic_store(&flags[b], 1u, __ATOMIC_RELEASE, __HIP_MEMORY_SCOPE_AGENT);
        }
        return;
    }

    // ================= SCAN ROLES =================
    float4* s_t = sh.scan.t;
    float*  red = sh.scan.red;

    if (blk < REC_BASE) {
        // ---- GT ROLE: min scan + gc bits ----
        int r = blk - GT_BASE;
        int b = r >> 2, chunk = r & 3;
        const float* ob = obj + ((size_t)b * N1V + (size_t)chunk * 2048) * 3;
        LOAD_PTS(ob)   // overlap obj preload with prep
        float nax[PPT], nay[PPT], naz[PPT], mgt[PPT];
#pragma unroll
        for (int i = 0; i < PPT; ++i) {
            nax[i] = -2.0f * px[i]; nay[i] = -2.0f * py[i]; naz[i] = -2.0f * pz[i];
            mgt[i] = 3.4e38f;
        }
        spin_wait(&flags[b], tid);
        const float4* gt4v = ws4 + (size_t)b * BATCH_F4;
        for (int j = tid; j < NVP; j += 256) s_t[j] = gt4v[j];
        if (tid == 0) red[0] = 0.0f;
        __syncthreads();

#pragma unroll 1
        for (int jq = 0; jq < NQ; ++jq) {
            int j = 4 * jq;
            float4 t0 = s_t[j], t1 = s_t[j+1], t2 = s_t[j+2], t3 = s_t[j+3];
#pragma unroll
            for (int i = 0; i < PPT; ++i) {
                float d0 = fmaf(nax[i], t0.x, fmaf(nay[i], t0.y, fmaf(naz[i], t0.z, t0.w)));
                float d1 = fmaf(nax[i], t1.x, fmaf(nay[i], t1.y, fmaf(naz[i], t1.z, t1.w)));
                float d2 = fmaf(nax[i], t2.x, fmaf(nay[i], t2.y, fmaf(naz[i], t2.z, t2.w)));
                float d3 = fmaf(nax[i], t3.x, fmaf(nay[i], t3.y, fmaf(naz[i], t3.z, t3.w)));
                float u = min3f(d0, d1, d2);           // v_min3
                mgt[i] = min3f(u, d3, mgt[i]);         // v_min3
            }
        }
        float lN_gt = 0.0f;
        unsigned int gcbits = 0;
#pragma unroll
        for (int i = 0; i < PPT; ++i) {
            float a2 = px[i]*px[i] + py[i]*py[i] + pz[i]*pz[i];
            float dgt = fmaxf(a2 + mgt[i], 0.0f);
            if (sqrtf(dgt) < 0.005f) { lN_gt += 1.0f; gcbits |= (1u << i); }
        }
        gcA[(size_t)r * 256 + tid] = (unsigned char)gcbits;
        atomicAdd(&red[0], lN_gt);
        __syncthreads();      // gc bytes + red done
        if (tid == 0) {
            __threadfence();
            __hip_atomic_store(&flags[NB + r], 1u, __ATOMIC_RELEASE, __HIP_MEMORY_SCOPE_AGENT);
            atomicAdd(&accB[b * 8 + 3], red[0]);
        }
    } else if (blk < CH_BASE) {
        // ---- REC ROLE: quad-argmin scan + epilogue + local consistency ----
        int r = blk - REC_BASE;
        int b = r >> 2, chunk = r & 3;
        const float* ob = obj + ((size_t)b * N1V + (size_t)chunk * 2048) * 3;
        LOAD_PTS(ob)
        float nax[PPT], nay[PPT], naz[PPT], m[PPT];
        int q[PPT];
#pragma unroll
        for (int i = 0; i < PPT; ++i) {
            nax[i] = -2.0f * px[i]; nay[i] = -2.0f * py[i]; naz[i] = -2.0f * pz[i];
            m[i] = 3.4e38f; q[i] = 0;
        }
        spin_wait(&flags[b], tid);
        const float4* base  = ws4 + (size_t)b * BATCH_F4;
        const float4* rec4p = base + NVP;
        const float4* nrm4p = base + 2 * NVP;
        for (int j = tid; j < NVP; j += 256) s_t[j] = rec4p[j];
        if (tid < 4) red[tid] = 0.0f;
        __syncthreads();

        float mp[PPT];
#pragma unroll 1
        for (int jq = 0; jq < SEG1Q; ++jq) {
            int j = 4 * jq;
            float4 t0 = s_t[j], t1 = s_t[j+1], t2 = s_t[j+2], t3 = s_t[j+3];
#pragma unroll
            for (int i = 0; i < PPT; ++i) {
                float d0 = fmaf(nax[i], t0.x, fmaf(nay[i], t0.y, fmaf(naz[i], t0.z, t0.w)));
                float d1 = fmaf(nax[i], t1.x, fmaf(nay[i], t1.y, fmaf(naz[i], t1.z, t1.w)));
                float d2 = fmaf(nax[i], t2.x, fmaf(nay[i], t2.y, fmaf(naz[i], t2.z, t2.w)));
                float d3 = fmaf(nax[i], t3.x, fmaf(nay[i], t3.y, fmaf(naz[i], t3.z, t3.w)));
                float u  = min3f(d0, d1, d2);
                float mn = min3f(u, d3, m[i]);
                q[i] = (mn < m[i]) ? jq : q[i];
                m[i] = mn;
            }
        }
#pragma unroll
        for (int i = 0; i < PPT; ++i) mp[i] = m[i];   // prior min snapshot
#pragma unroll 1
        for (int jq = SEG1Q; jq < NQ; ++jq) {
            int j = 4 * jq;
            float4 t0 = s_t[j], t1 = s_t[j+1], t2 = s_t[j+2], t3 = s_t[j+3];
#pragma unroll
            for (int i = 0; i < PPT; ++i) {
                float d0 = fmaf(nax[i], t0.x, fmaf(nay[i], t0.y, fmaf(naz[i], t0.z, t0.w)));
                float d1 = fmaf(nax[i], t1.x, fmaf(nay[i], t1.y, fmaf(naz[i], t1.z, t1.w)));
                float d2 = fmaf(nax[i], t2.x, fmaf(nay[i], t2.y, fmaf(naz[i], t2.z, t2.w)));
                float d3 = fmaf(nax[i], t3.x, fmaf(nay[i], t3.y, fmaf(naz[i], t3.z, t3.w)));
                float u  = min3f(d0, d1, d2);
                float mn = min3f(u, d3, m[i]);
                q[i] = (mn < m[i]) ? jq : q[i];
                m[i] = mn;
            }
        }
        // ---- inline epilogue (bit-identical math to previous version) ----
        float lS_cmap = 0.0f, lN_cmap = 0.0f, lS_pen = 0.0f;
        unsigned int rcbits = 0;
#pragma unroll
        for (int i = 0; i < PPT; ++i) {
            float a2 = px[i]*px[i] + py[i]*py[i] + pz[i]*pz[i];
            float drec = fmaxf(a2 + (m[i]  - BIAS), 0.0f);
            float dpri = fmaxf(a2 + (mp[i] - BIAS), 0.0f);
            bool cm = drec < 1e-4f;
            bool rc = sqrtf(drec) < 0.005f;
            if (cm) { lS_cmap += dpri; lN_cmap += 1.0f; }
            if (rc) rcbits |= (1u << i);
            int jr = 4 * q[i];
            float4 t0 = s_t[jr], t1 = s_t[jr+1], t2 = s_t[jr+2], t3 = s_t[jr+3];
            float d0 = fmaf(nax[i], t0.x, fmaf(nay[i], t0.y, fmaf(naz[i], t0.z, t0.w)));
            float d1 = fmaf(nax[i], t1.x, fmaf(nay[i], t1.y, fmaf(naz[i], t1.z, t1.w)));
            float d2 = fmaf(nax[i], t2.x, fmaf(nay[i], t2.y, fmaf(naz[i], t2.z, t2.w)));
            float d3 = fmaf(nax[i], t3.x, fmaf(nay[i], t3.y, fmaf(naz[i], t3.z, t3.w)));
            float mmin = fminf(fminf(d0, d1), fminf(d2, d3));
            int off = (d0 == mmin) ? 0 : ((d1 == mmin) ? 1 : ((d2 == mmin) ? 2 : 3));
            int jstar = jr + off;
            float4 tS = s_t[jstar];
            float4 nr = nrm4p[jstar];
            float ddot = (tS.x - px[i]) * nr.x + (tS.y - py[i]) * nr.y
                       + (tS.z - pz[i]) * nr.z;
            if (ddot > 0.0f) lS_pen += drec;
        }
        atomicAdd(&red[0], lS_cmap);
        atomicAdd(&red[1], lN_cmap);
        atomicAdd(&red[2], lS_pen);
        // consistency: AND our in-register rc bits with gt block's gc byte
        spin_wait(&flags[NB + r], tid);   // barrier also completes red[] adds
        unsigned int gcb = gcA[(size_t)r * 256 + tid];
        float lcons = (float)__popc(rcbits & gcb);
        atomicAdd(&red[3], lcons);
        __syncthreads();
        if (tid == 0) atomicAdd(&accB[b * 8 + 1], red[0]);
        if (tid == 1) atomicAdd(&accB[b * 8 + 2], red[1]);
        if (tid == 2) atomicAdd(&accB[b * 8 + 5], red[2]);
        if (tid == 3) atomicAdd(&accB[b * 8 + 4], red[3]);
    } else {
        // ---- CHAMFER ROLE (4 sources/thread) ----
        int c   = blk - CH_BASE;
        int b   = c >> 1;
        int dir = c & 1;           // 0: rec->gt, 1: gt->rec
        spin_wait(&flags[b], tid);
        const float4* base = ws4 + (size_t)b * BATCH_F4;
        const float4* srcv = dir ? base : (base + NVP);   // gt4 : rec4p
        const float4* tgtv = dir ? (base + NVP) : base;   // rec4p : gt4
        for (int j = tid; j < NVP; j += 256) s_t[j] = tgtv[j];
        if (tid == 0) red[0] = 0.0f;
        __syncthreads();

        const int CPT = 4;
        float nax[CPT], nay[CPT], naz[CPT], a2[CPT], m[CPT];
        bool valid[CPT];
#pragma unroll
        for (int k = 0; k < CPT; ++k) {
            int p = tid + 256 * k;
            valid[k] = (p < NV);
            float4 s = srcv[valid[k] ? p : 0];
            nax[k] = -2.0f * s.x; nay[k] = -2.0f * s.y; naz[k] = -2.0f * s.z;
            a2[k] = s.w;                  // one of src/tgt carries +BIAS
            m[k] = 3.4e38f;
        }
#pragma unroll 1
        for (int j = 0; j < NVP; j += 4) {
            float4 t0 = s_t[j], t1 = s_t[j+1], t2 = s_t[j+2], t3 = s_t[j+3];
#pragma unroll
            for (int k = 0; k < CPT; ++k) {
                float d0 = fmaf(nax[k], t0.x, fmaf(nay[k], t0.y, fmaf(naz[k], t0.z, t0.w)));
                float d1 = fmaf(nax[k], t1.x, fmaf(nay[k], t1.y, fmaf(naz[k], t1.z, t1.w)));
                float d2 = fmaf(nax[k], t2.x, fmaf(nay[k], t2.y, fmaf(naz[k], t2.z, t2.w)));
                float d3 = fmaf(nax[k], t3.x, fmaf(nay[k], t3.y, fmaf(naz[k], t3.z, t3.w)));
                float u = min3f(d0, d1, d2);
                m[k] = min3f(u, d3, m[k]);
            }
        }
        float local = 0.0f;
#pragma unroll
        for (int k = 0; k < CPT; ++k)
            if (valid[k]) local += fmaxf(a2[k] + m[k] - BIAS, 0.0f);
        atomicAdd(&red[0], local);
        __syncthreads();
        if (tid == 0) atomicAdd(&accB[b * 8 + 0], red[0]);
    }

    // ================= TICKET + FINALIZE (scan roles only) =================
    __syncthreads();    // all global atomicAdds of this block retired
    if (tid == 0) {
        __threadfence();
        s_tk = atomicAdd(&flags[NB + GT_BLOCKS], 1u);
    }
    __syncthreads();
    if (s_tk == SCAN_BLOCKS - 1) {
        if (tid < 8) red[tid] = 0.0f;
        __syncthreads();
        float l0=0.f,l1=0.f,l2=0.f,l3=0.f,l4=0.f,l5=0.f;
        for (int b2 = tid; b2 < NB; b2 += 256) {
            const float* row = accB + (size_t)b2 * 8;
            l0 += __hip_atomic_load(row + 0, __ATOMIC_RELAXED, __HIP_MEMORY_SCOPE_AGENT);
            l1 += __hip_atomic_load(row + 1, __ATOMIC_RELAXED, __HIP_MEMORY_SCOPE_AGENT);
            l2 += __hip_atomic_load(row + 2, __ATOMIC_RELAXED, __HIP_MEMORY_SCOPE_AGENT);
            l3 += __hip_atomic_load(row + 3, __ATOMIC_RELAXED, __HIP_MEMORY_SCOPE_AGENT);
            l4 += __hip_atomic_load(row + 4, __ATOMIC_RELAXED, __HIP_MEMORY_SCOPE_AGENT);
            l5 += __hip_atomic_load(row + 5, __ATOMIC_RELAXED, __HIP_MEMORY_SCOPE_AGENT);
        }
        atomicAdd(&red[0], l0); atomicAdd(&red[1], l1); atomicAdd(&red[2], l2);
        atomicAdd(&red[3], l3); atomicAdd(&red[4], l4); atomicAdd(&red[5], l5);
        float s_param = 0.0f, s_kld = 0.0f;
        for (int i = tid; i < NB * NPAR; i += 256) {
            float d = rp[i] - xp[i];
            s_param += d * d;
        }
        for (int i = tid; i < NB * NZ; i += 256) {
            float mv = mean[i], lv = log_var[i];
            s_kld += 1.0f + lv - mv * mv - expf(lv);
        }
        atomicAdd(&red[6], s_param);
        atomicAdd(&red[7], s_kld);
        __syncthreads();
        if (tid == 0) {
            const float fB = 64.0f;
            float recon_loss  = red[0] / fB;
            float cmap_loss   = 3000.0f * red[1] / (fB * red[2]);
            float consistency = -5.0f * red[4] / (red[3] + 0.0001f);
            float penetr      = 100.0f * red[5] / fB;
            float param_loss  = red[6] / fB;
            float KLD         = -0.5f * red[7] / fB * 10.0f;
            out[0] = (recon_loss + KLD) + 0.1f * param_loss + 1000.0f * cmap_loss
                   + 10.0f * consistency + 10.0f * penetr;
        }
    }
}

extern "C" void kernel_launch(void* const* d_in, const int* in_sizes, int n_in,
                              void* d_out, int out_size, void* d_ws, size_t ws_size,
                              hipStream_t stream) {
    (void)in_sizes; (void)n_in; (void)out_size; (void)ws_size;
    const float* obj     = (const float*)d_in[0];
    const float* recon   = (const float*)d_in[1];
    const float* gt      = (const float*)d_in[2];
    const float* mean    = (const float*)d_in[3];
    const float* log_var = (const float*)d_in[4];
    const float* rp      = (const float*)d_in[5];
    const float* xp      = (const float*)d_in[6];
    const int*   faces   = (const int*)d_in[7];
    float* wsf = (float*)d_ws;
    float4* ws4 = (float4*)d_ws;
    float* accB = wsf + ACCB_OFF;
    unsigned int* flags = (unsigned int*)(wsf + FLAGS_OFF);
    unsigned char* gcA = (unsigned char*)(wsf + GC_OFF);
    float* out = (float*)d_out;

    hipMemsetAsync(flags, 0, NFLAGS * sizeof(unsigned int), stream);
    k_all<<<NBLOCKS, 256, 0, stream>>>(obj, recon, gt, faces, mean, log_var,
                                       rp, xp, ws4, accB, flags, gcA, out);
}

// Round 3
// 206.949 us; speedup vs baseline: 1.1831x; 1.1831x over previous
//
#include <hip/hip_runtime.h>
#include <math.h>

// Problem constants (from reference setup_inputs)
#define NB     64      // batch
#define N1V    8192    // obj points per batch
#define NPTS   (NB * N1V)
#define NV     778     // recon / gt verts
#define NVP    780     // padded to multiple of 4
#define NQ     195     // target quads
#define SEG1Q  51      // first 51 quads = 204 permuted targets = PRIOR set
#define NFACE  1538
#define NZ     64
#define NPAR   61
#define NPRIOR 204
#define PPT    8       // obj points per thread (rec/gt roles)
#define BIAS   0.0625f // 2|a||t| <= 0.06 < BIAS -> biased rec partials stay >= 0
#define TPB    128     // threads per block in k_fused (128 -> 1280 blocks = 5/CU exact)

// k_fused roles: rec 512 (b= r>>3, chunk=r&7, 1024 pts), gt 512, cham 256
#define REC_BLOCKS 512
#define GT_BLOCKS  512
#define CH_BLOCKS  256
#define NROLE_BLOCKS (REC_BLOCKS + GT_BLOCKS + CH_BLOCKS)   // 1280
#define CMB_BLOCKS 64                  // 64*256 uints over rc/gc words

// ws float4 layout per batch (BATCH_F4 float4s):
//   [0,780)     gt4    (x,y,z,|t|^2)  original order, pads w=1e30
//   [780,1560)  rec4p  (x,y,z,|t|^2+BIAS) PERMUTED (prior first), pads w=1e30
//   [1560,2340) nrm4p  (nx,ny,nz,0)   PERMUTED to match rec4p
#define BATCH_F4 2352                  // padded stride
// float offsets in ws
#define ACC_OFF (NB * BATCH_F4 * 4)   // acc[16]: [2..7] sums, [15] ticket
#define RC_OFF  (ACC_OFF + 16)        // uchar[NPTS/8] rec-cmap bits (1/pt)
#define GC_OFF  (RC_OFF + NPTS / 32)  // uchar[NPTS/8] gt-cmap bits
// acc slots: 2 chamfer, 3 S_cmap, 4 N_cmap, 5 N_gt, 6 N_cons, 7 S_pen

// ---- compile-time prior permutation (pure function of the static index list) ----
static constexpr int PRIOR_LIST[NPRIOR] = {
  697,698,699,700,712,713,714,715,737,738,739,740,741,743,744,745,746,748,749,750,
  753,754,755,756,757,758,759,760,761,762,763,764,765,766,767,768,
  46,47,48,49,164,165,166,167,194,195,223,237,238,280,281,298,301,317,320,323,
  324,325,326,327,328,329,330,331,332,333,340,341,342,343,344,345,346,347,348,349,
  350,351,352,353,354,355,
  356,357,358,359,375,376,386,387,396,397,402,403,413,429,433,434,435,436,437,438,
  439,440,441,442,443,444,452,453,454,455,456,459,460,461,462,463,464,465,466,467,
  468,469,470,471,484,485,486,496,497,506,507,513,514,524,545,546,547,548,549,550,
  551,552,553,555,563,564,565,566,567,570,572,573,574,575,576,577,578,
  580,581,582,583,600,601,602,614,615,624,625,630,631,641,663,664,665,666,667,668,
  670,672,680,681,682,683,684,686,687,688,689,690,691,692,693,694,695,
  73,96,98,99,772,774,775,777
};

struct PermT { unsigned short v[NV]; };
static constexpr PermT make_perm() {
    PermT t{};
    bool mem[NV] = {};
    for (int i = 0; i < NPRIOR; ++i) mem[PRIOR_LIST[i]] = true;
    int a = 0, b = NPRIOR;
    for (int j = 0; j < NV; ++j) {
        if (mem[j]) t.v[a++] = (unsigned short)j;
        else        t.v[b++] = (unsigned short)j;
    }
    return t;
}
__device__ __constant__ PermT c_perm = make_perm();

// ---------------- Kernel 0: permuted target arrays + normals + acc init ------
__global__ __launch_bounds__(256) void k_prep(const float* __restrict__ recon,
                                              const float* __restrict__ gt,
                                              const int* __restrict__ faces,
                                              float4* __restrict__ ws4,
                                              float* __restrict__ acc) {
    int b = blockIdx.x, tid = threadIdx.x;
    if (b == 0 && tid < 16) acc[tid] = 0.0f;
    __shared__ float4 s_r[NV];
    __shared__ float s_vnx[NV], s_vny[NV], s_vnz[NV];

    const float* rb = recon + (size_t)b * NV * 3;
    const float* gb = gt    + (size_t)b * NV * 3;
    float4* gt4   = ws4 + (size_t)b * BATCH_F4;
    float4* rec4p = gt4 + NVP;
    float4* nrm4p = rec4p + NVP;
    for (int j = tid; j < NV; j += 256) {
        float x = rb[3*j], y = rb[3*j+1], z = rb[3*j+2];
        s_r[j] = make_float4(x, y, z, x*x + y*y + z*z + BIAS);
        x = gb[3*j]; y = gb[3*j+1]; z = gb[3*j+2];
        gt4[j] = make_float4(x, y, z, x*x + y*y + z*z);
        s_vnx[j] = 0.0f; s_vny[j] = 0.0f; s_vnz[j] = 0.0f;
    }
    if (tid < 2) gt4[NV + tid] = make_float4(0.f, 0.f, 0.f, 1e30f);
    __syncthreads();
    for (int f = tid; f < NFACE; f += 256) {
        int i0 = faces[3*f], i1 = faces[3*f+1], i2 = faces[3*f+2];
        float4 p0 = s_r[i0], p1 = s_r[i1], p2 = s_r[i2];
        float e1x = p1.x - p0.x, e1y = p1.y - p0.y, e1z = p1.z - p0.z;
        float e2x = p2.x - p0.x, e2y = p2.y - p0.y, e2z = p2.z - p0.z;
        float fx = e1y * e2z - e1z * e2y;
        float fy = e1z * e2x - e1x * e2z;
        float fz = e1x * e2y - e1y * e2x;
        atomicAdd(&s_vnx[i0], fx); atomicAdd(&s_vny[i0], fy); atomicAdd(&s_vnz[i0], fz);
        atomicAdd(&s_vnx[i1], fx); atomicAdd(&s_vny[i1], fy); atomicAdd(&s_vnz[i1], fz);
        atomicAdd(&s_vnx[i2], fx); atomicAdd(&s_vny[i2], fy); atomicAdd(&s_vnz[i2], fz);
    }
    __syncthreads();
    for (int j = tid; j < NVP; j += 256) {
        if (j < NV) {
            int src = c_perm.v[j];
            rec4p[j] = s_r[src];
            float x = s_vnx[src], y = s_vny[src], z = s_vnz[src];
            float inv = 1.0f / (sqrtf(x*x + y*y + z*z) + 1e-12f);
            nrm4p[j] = make_float4(x * inv, y * inv, z * inv, 0.0f);
        } else {
            rec4p[j] = make_float4(0.f, 0.f, 0.f, 1e30f);
            nrm4p[j] = make_float4(0.f, 0.f, 1.f, 0.0f);
        }
    }
}

#define LOAD_PTS(ob)                                                          \
    const float4* ob4 = (const float4*)((ob) + (size_t)tid * 24);             \
    float4 q0 = ob4[0], q1 = ob4[1], q2 = ob4[2],                             \
           q3 = ob4[3], q4 = ob4[4], q5 = ob4[5];                             \
    float px[PPT], py[PPT], pz[PPT];                                          \
    px[0]=q0.x; py[0]=q0.y; pz[0]=q0.z;  px[1]=q0.w; py[1]=q1.x; pz[1]=q1.y;  \
    px[2]=q1.z; py[2]=q1.w; pz[2]=q2.x;  px[3]=q2.y; py[3]=q2.z; pz[3]=q2.w;  \
    px[4]=q3.x; py[4]=q3.y; pz[4]=q3.z;  px[5]=q3.w; py[5]=q4.x; pz[5]=q4.y;  \
    px[6]=q4.z; py[6]=q4.w; pz[6]=q5.x;  px[7]=q5.y; py[7]=q5.z; pz[7]=q5.w;

__device__ __forceinline__ float min3f(float a, float b, float c) {
    return fminf(fminf(a, b), c);
}

// ---------------- Fused role kernel (128-thr blocks, 1280 total = 5/CU) -----
// [0,512): rec quad-argmin + full epilogue  [512,1024): gt min + gc bits
// [1024,1280): chamfer
__global__ __launch_bounds__(TPB) void k_fused(const float* __restrict__ obj,
                                               const float4* __restrict__ ws4,
                                               float* __restrict__ acc,
                                               unsigned char* __restrict__ rcA,
                                               unsigned char* __restrict__ gcA) {
    __shared__ float4 s_t[NVP];
    __shared__ float s_red[3];
    int tid = threadIdx.x;
    int blk = blockIdx.x;

    if (blk < REC_BLOCKS) {
        // ============ REC ROLE: scan + inline epilogue ============
        int b = blk >> 3, chunk = blk & 7;
        const float4* base = ws4 + (size_t)b * BATCH_F4;
        const float4* rec4p = base + NVP;
        const float4* nrm4p = base + 2 * NVP;
        for (int j = tid; j < NVP; j += TPB) s_t[j] = rec4p[j];
        if (tid < 3) s_red[tid] = 0.0f;
        __syncthreads();

        const float* ob = obj + ((size_t)b * N1V + (size_t)chunk * 1024) * 3;
        LOAD_PTS(ob)
        float nax[PPT], nay[PPT], naz[PPT], m[PPT];
        int q[PPT];
#pragma unroll
        for (int i = 0; i < PPT; ++i) {
            nax[i] = -2.0f * px[i]; nay[i] = -2.0f * py[i]; naz[i] = -2.0f * pz[i];
            m[i] = 3.4e38f; q[i] = 0;
        }
        float mp[PPT];
#pragma unroll 2
        for (int jq = 0; jq < SEG1Q; ++jq) {
            int j = 4 * jq;
            float4 t0 = s_t[j], t1 = s_t[j+1], t2 = s_t[j+2], t3 = s_t[j+3];
#pragma unroll
            for (int i = 0; i < PPT; ++i) {
                float d0 = fmaf(nax[i], t0.x, fmaf(nay[i], t0.y, fmaf(naz[i], t0.z, t0.w)));
                float d1 = fmaf(nax[i], t1.x, fmaf(nay[i], t1.y, fmaf(naz[i], t1.z, t1.w)));
                float d2 = fmaf(nax[i], t2.x, fmaf(nay[i], t2.y, fmaf(naz[i], t2.z, t2.w)));
                float d3 = fmaf(nax[i], t3.x, fmaf(nay[i], t3.y, fmaf(naz[i], t3.z, t3.w)));
                float u  = min3f(d0, d1, d2);
                float mn = min3f(u, d3, m[i]);
                q[i] = (mn < m[i]) ? jq : q[i];
                m[i] = mn;
            }
        }
#pragma unroll
        for (int i = 0; i < PPT; ++i) mp[i] = m[i];   // prior min snapshot
#pragma unroll 2
        for (int jq = SEG1Q; jq < NQ; ++jq) {
            int j = 4 * jq;
            float4 t0 = s_t[j], t1 = s_t[j+1], t2 = s_t[j+2], t3 = s_t[j+3];
#pragma unroll
            for (int i = 0; i < PPT; ++i) {
                float d0 = fmaf(nax[i], t0.x, fmaf(nay[i], t0.y, fmaf(naz[i], t0.z, t0.w)));
                float d1 = fmaf(nax[i], t1.x, fmaf(nay[i], t1.y, fmaf(naz[i], t1.z, t1.w)));
                float d2 = fmaf(nax[i], t2.x, fmaf(nay[i], t2.y, fmaf(naz[i], t2.z, t2.w)));
                float d3 = fmaf(nax[i], t3.x, fmaf(nay[i], t3.y, fmaf(naz[i], t3.z, t3.w)));
                float u  = min3f(d0, d1, d2);
                float mn = min3f(u, d3, m[i]);
                q[i] = (mn < m[i]) ? jq : q[i];
                m[i] = mn;
            }
        }
        // ---- inline epilogue ----
        float lS_cmap = 0.0f, lN_cmap = 0.0f, lS_pen = 0.0f;
        unsigned int rcbits = 0;
#pragma unroll
        for (int i = 0; i < PPT; ++i) {
            float a2 = px[i]*px[i] + py[i]*py[i] + pz[i]*pz[i];
            float drec = fmaxf(a2 + (m[i]  - BIAS), 0.0f);
            float dpri = fmaxf(a2 + (mp[i] - BIAS), 0.0f);
            bool cm = drec < 1e-4f;
            bool rc = sqrtf(drec) < 0.005f;
            if (cm) { lS_cmap += dpri; lN_cmap += 1.0f; }
            if (rc) rcbits |= (1u << i);
            // winning-quad re-eval from LDS for jstar (bit-identical fma chain)
            int jr = 4 * q[i];
            float4 t0 = s_t[jr], t1 = s_t[jr+1], t2 = s_t[jr+2], t3 = s_t[jr+3];
            float d0 = fmaf(nax[i], t0.x, fmaf(nay[i], t0.y, fmaf(naz[i], t0.z, t0.w)));
            float d1 = fmaf(nax[i], t1.x, fmaf(nay[i], t1.y, fmaf(naz[i], t1.z, t1.w)));
            float d2 = fmaf(nax[i], t2.x, fmaf(nay[i], t2.y, fmaf(naz[i], t2.z, t2.w)));
            float d3 = fmaf(nax[i], t3.x, fmaf(nay[i], t3.y, fmaf(naz[i], t3.z, t3.w)));
            float mmin = fminf(fminf(d0, d1), fminf(d2, d3));
            int off = (d0 == mmin) ? 0 : ((d1 == mmin) ? 1 : ((d2 == mmin) ? 2 : 3));
            int jstar = jr + off;
            float4 tS = s_t[jstar];
            float4 nr = nrm4p[jstar];
            float ddot = (tS.x - px[i]) * nr.x + (tS.y - py[i]) * nr.y
                       + (tS.z - pz[i]) * nr.z;
            if (ddot > 0.0f) lS_pen += drec;
        }
        rcA[(size_t)blk * TPB + tid] = (unsigned char)rcbits;
        atomicAdd(&s_red[0], lS_cmap);
        atomicAdd(&s_red[1], lN_cmap);
        atomicAdd(&s_red[2], lS_pen);
        __syncthreads();
        if (tid == 0) atomicAdd(&acc[3], s_red[0]);
        if (tid == 1) atomicAdd(&acc[4], s_red[1]);
        if (tid == 2) atomicAdd(&acc[7], s_red[2]);
        return;
    }

    if (blk < REC_BLOCKS + GT_BLOCKS) {
        // ============ GT ROLE: min scan + gc bits ============
        int r = blk - REC_BLOCKS;
        int b = r >> 3, chunk = r & 7;
        const float4* gt4v = ws4 + (size_t)b * BATCH_F4;
        for (int j = tid; j < NVP; j += TPB) s_t[j] = gt4v[j];
        if (tid == 0) s_red[0] = 0.0f;
        __syncthreads();

        const float* ob = obj + ((size_t)b * N1V + (size_t)chunk * 1024) * 3;
        LOAD_PTS(ob)
        float nax[PPT], nay[PPT], naz[PPT], mgt[PPT];
#pragma unroll
        for (int i = 0; i < PPT; ++i) {
            nax[i] = -2.0f * px[i]; nay[i] = -2.0f * py[i]; naz[i] = -2.0f * pz[i];
            mgt[i] = 3.4e38f;
        }
#pragma unroll 2
        for (int jq = 0; jq < NQ; ++jq) {
            int j = 4 * jq;
            float4 t0 = s_t[j], t1 = s_t[j+1], t2 = s_t[j+2], t3 = s_t[j+3];
#pragma unroll
            for (int i = 0; i < PPT; ++i) {
                float d0 = fmaf(nax[i], t0.x, fmaf(nay[i], t0.y, fmaf(naz[i], t0.z, t0.w)));
                float d1 = fmaf(nax[i], t1.x, fmaf(nay[i], t1.y, fmaf(naz[i], t1.z, t1.w)));
                float d2 = fmaf(nax[i], t2.x, fmaf(nay[i], t2.y, fmaf(naz[i], t2.z, t2.w)));
                float d3 = fmaf(nax[i], t3.x, fmaf(nay[i], t3.y, fmaf(naz[i], t3.z, t3.w)));
                float u = min3f(d0, d1, d2);
                mgt[i] = min3f(u, d3, mgt[i]);
            }
        }
        float lN_gt = 0.0f;
        unsigned int gcbits = 0;
#pragma unroll
        for (int i = 0; i < PPT; ++i) {
            float a2 = px[i]*px[i] + py[i]*py[i] + pz[i]*pz[i];
            float dgt = fmaxf(a2 + mgt[i], 0.0f);
            if (sqrtf(dgt) < 0.005f) { lN_gt += 1.0f; gcbits |= (1u << i); }
        }
        gcA[(size_t)r * TPB + tid] = (unsigned char)gcbits;
        atomicAdd(&s_red[0], lN_gt);
        __syncthreads();
        if (tid == 0) atomicAdd(&acc[5], s_red[0]);
        return;
    }

    // ============ CHAMFER ROLE (4 sources/thread, half-range blocks) ============
    {
        int c    = blk - (REC_BLOCKS + GT_BLOCKS);
        int b    = c >> 2;
        int sub  = c & 3;
        int dir  = sub & 1;        // 0: rec->gt, 1: gt->rec
        int half = sub >> 1;       // source range [half*512, half*512+512)
        const float4* base = ws4 + (size_t)b * BATCH_F4;
        const float4* srcv = dir ? base : (base + NVP);   // gt4 : rec4p
        const float4* tgtv = dir ? (base + NVP) : base;   // rec4p : gt4
        for (int j = tid; j < NVP; j += TPB) s_t[j] = tgtv[j];
        if (tid == 0) s_red[0] = 0.0f;
        __syncthreads();

        const int CPT = 4;
        float nax[CPT], nay[CPT], naz[CPT], a2[CPT], m[CPT];
        bool valid[CPT];
#pragma unroll
        for (int k = 0; k < CPT; ++k) {
            int p = half * 512 + k * TPB + tid;
            valid[k] = (p < NV);
            float4 s = srcv[valid[k] ? p : 0];
            nax[k] = -2.0f * s.x; nay[k] = -2.0f * s.y; naz[k] = -2.0f * s.z;
            a2[k] = s.w;                  // one of src/tgt carries +BIAS
            m[k] = 3.4e38f;
        }
#pragma unroll 2
        for (int j = 0; j < NVP; j += 4) {
            float4 t0 = s_t[j], t1 = s_t[j+1], t2 = s_t[j+2], t3 = s_t[j+3];
#pragma unroll
            for (int k = 0; k < CPT; ++k) {
                float d0 = fmaf(nax[k], t0.x, fmaf(nay[k], t0.y, fmaf(naz[k], t0.z, t0.w)));
                float d1 = fmaf(nax[k], t1.x, fmaf(nay[k], t1.y, fmaf(naz[k], t1.z, t1.w)));
                float d2 = fmaf(nax[k], t2.x, fmaf(nay[k], t2.y, fmaf(naz[k], t2.z, t2.w)));
                float d3 = fmaf(nax[k], t3.x, fmaf(nay[k], t3.y, fmaf(naz[k], t3.z, t3.w)));
                float u = min3f(d0, d1, d2);
                m[k] = min3f(u, d3, m[k]);
            }
        }
        float local = 0.0f;
#pragma unroll
        for (int k = 0; k < CPT; ++k)
            if (valid[k]) local += fmaxf(a2[k] + m[k] - BIAS, 0.0f);
        atomicAdd(&s_red[0], local);
        __syncthreads();
        if (tid == 0) atomicAdd(&acc[2], s_red[0]);
    }
}

// ---------------- Combine (popcount rc&gc) + finalize (ticket) ----------------
__global__ __launch_bounds__(256) void k_combine(float* __restrict__ acc,
                                                 const unsigned int* __restrict__ rcW,
                                                 const unsigned int* __restrict__ gcW,
                                                 const float* __restrict__ mean,
                                                 const float* __restrict__ log_var,
                                                 const float* __restrict__ rp,
                                                 const float* __restrict__ xp,
                                                 float* __restrict__ out) {
    int blk = blockIdx.x, tid = threadIdx.x;
    __shared__ float s_red[2];
    __shared__ unsigned int s_ticket;
    if (tid < 2) s_red[tid] = 0.0f;
    __syncthreads();
    int idx = blk * 256 + tid;                    // 16384 uints = NPTS/8 bytes
    unsigned int rc = rcW[idx], gc = gcW[idx];
    float cnt = (float)__popc(rc & gc);
    atomicAdd(&s_red[0], cnt);
    __syncthreads();
    if (tid == 0) atomicAdd(&acc[6], s_red[0]);
    __threadfence();
    if (tid == 0) s_ticket = atomicAdd((unsigned int*)&acc[15], 1u);
    __syncthreads();

    if (s_ticket == CMB_BLOCKS - 1) {
        if (tid < 2) s_red[tid] = 0.0f;
        __syncthreads();
        float s_param = 0.0f, s_kld = 0.0f;
        for (int i = tid; i < NB * NPAR; i += 256) {
            float d = rp[i] - xp[i];
            s_param += d * d;
        }
        for (int i = tid; i < NB * NZ; i += 256) {
            float m = mean[i], lv = log_var[i];
            s_kld += 1.0f + lv - m * m - expf(lv);
        }
        atomicAdd(&s_red[0], s_param);
        atomicAdd(&s_red[1], s_kld);
        __syncthreads();
        if (tid == 0) {
            const float fB = 64.0f;
            float a2v = atomicAdd(&acc[2], 0.0f);
            float a3  = atomicAdd(&acc[3], 0.0f);
            float a4  = atomicAdd(&acc[4], 0.0f);
            float a5  = atomicAdd(&acc[5], 0.0f);
            float a6  = atomicAdd(&acc[6], 0.0f);
            float a7  = atomicAdd(&acc[7], 0.0f);
            float param_loss  = s_red[0] / fB;
            float KLD         = -0.5f * s_red[1] / fB * 10.0f;
            float recon_loss  = a2v / fB;
            float cmap_loss   = 3000.0f * a3 / (fB * a4);
            float consistency = -5.0f * a6 / (a5 + 0.0001f);
            float penetr      = 100.0f * a7 / fB;
            out[0] = (recon_loss + KLD) + 0.1f * param_loss + 1000.0f * cmap_loss
                   + 10.0f * consistency + 10.0f * penetr;
        }
    }
}

extern "C" void kernel_launch(void* const* d_in, const int* in_sizes, int n_in,
                              void* d_out, int out_size, void* d_ws, size_t ws_size,
                              hipStream_t stream) {
    (void)in_sizes; (void)n_in; (void)out_size; (void)ws_size;
    const float* obj     = (const float*)d_in[0];
    const float* recon   = (const float*)d_in[1];
    const float* gt      = (const float*)d_in[2];
    const float* mean    = (const float*)d_in[3];
    const float* log_var = (const float*)d_in[4];
    const float* rp      = (const float*)d_in[5];
    const float* xp      = (const float*)d_in[6];
    const int*   faces   = (const int*)d_in[7];
    float* acc  = (float*)d_ws + ACC_OFF;
    float4* ws4 = (float4*)d_ws;
    unsigned char* rcA = (unsigned char*)((float*)d_ws + RC_OFF);
    unsigned char* gcA = (unsigned char*)((float*)d_ws + GC_OFF);
    float* out  = (float*)d_out;

    k_prep   <<<NB,           256, 0, stream>>>(recon, gt, faces, ws4, acc);
    k_fused  <<<NROLE_BLOCKS, TPB, 0, stream>>>(obj, ws4, acc, rcA, gcA);
    k_combine<<<CMB_BLOCKS,   256, 0, stream>>>(acc, (const unsigned int*)rcA,
                                                (const unsigned int*)gcA,
                                                mean, log_var, rp, xp, out);
}